// Round 1
// baseline (1085.488 us; speedup 1.0000x reference)
//
#include <hip/hip_runtime.h>
#include <math.h>

#define B_ 16
#define HEADS_ 8
#define G_ 64          // == L (sequence length of the SSM)
#define DH_ 64
#define N_ 3131
#define DM_ 512
#define NH_ 8
#define DINPROJ_ 1042
#define CONVDIM_ 514
#define DIM_ 512

#define OUT0_OFS 0
#define OUT1_OFS (B_*N_*DIM_)                    // 25,649,152
#define OUT2_OFS (B_*N_*DIM_ + B_*HEADS_*G_*DH_) // 26,173,440

__device__ __forceinline__ float siluf(float v){ return v / (1.f + expf(-v)); }
__device__ __forceinline__ float softplusf(float v){ return (v > 20.f) ? v : log1pf(expf(v)); }

// ---------------------------------------------------------------------------
// k1: zxbcdt[b,l,j] = sum_d u[b,l,d] * w_in[j,d]
//     u[b,l,h*64+c] = slice_token[b,h,l,c]
// grid: B_*G_ blocks, 256 threads
__global__ void k1_inproj(const float* __restrict__ st,
                          const float* __restrict__ w_in,
                          float* __restrict__ zx) {
    int bl = blockIdx.x; int b = bl >> 6, l = bl & 63;
    __shared__ float u[DM_];
    for (int d = threadIdx.x; d < DM_; d += 256) {
        int h = d >> 6, c = d & 63;
        u[d] = st[(((b*HEADS_ + h)*G_ + l) << 6) + c];
    }
    __syncthreads();
    const float4* u4p = (const float4*)u;
    for (int j = threadIdx.x; j < DINPROJ_; j += 256) {
        const float4* wr = (const float4*)(w_in + (size_t)j * DM_);
        float s = 0.f;
#pragma unroll 8
        for (int q = 0; q < DM_/4; q++) {
            float4 w4 = wr[q]; float4 uu = u4p[q];
            s += w4.x*uu.x + w4.y*uu.y + w4.z*uu.z + w4.w*uu.w;
        }
        zx[(size_t)bl * DINPROJ_ + j] = s;
    }
}

// ---------------------------------------------------------------------------
// k2: conv3 + silu -> x, Bv, Cv ; silu(z) ; softplus dt fw/bw ; dcoef
// grid: B_*G_ blocks, 256 threads
__global__ void k2_conv(const float* __restrict__ zx,
                        const float* __restrict__ conv_w,
                        const float* __restrict__ conv_b,
                        const float* __restrict__ dt_bias,
                        const float* __restrict__ fc_D_w,
                        const float* __restrict__ Dvec,
                        float* __restrict__ x, float* __restrict__ zs,
                        float* __restrict__ Bv, float* __restrict__ Cv,
                        float* __restrict__ dtf, float* __restrict__ dtb,
                        float* __restrict__ dco) {
    int bl = blockIdx.x; int b = bl >> 6, l = bl & 63;
    __shared__ float sx[DM_];
    const float* zrow = zx + (size_t)bl * DINPROJ_;

    for (int ch = threadIdx.x; ch < CONVDIM_; ch += 256) {
        float v = conv_b[ch];
#pragma unroll
        for (int k = 0; k < 3; k++) {
            int t = l - 2 + k;
            if (t >= 0) v += conv_w[ch*3 + k] * zx[(size_t)(b*G_ + t) * DINPROJ_ + DM_ + ch];
        }
        float sv = siluf(v);
        if (ch < DM_)      { x[(size_t)bl*DM_ + ch] = sv; sx[ch] = sv; }
        else if (ch == DM_){ Bv[bl] = sv; }
        else               { Cv[bl] = sv; }
    }
    for (int d = threadIdx.x; d < DM_; d += 256) {
        zs[(size_t)bl*DM_ + d] = siluf(zrow[d]);
    }
    if (threadIdx.x < 16) {
        int i = threadIdx.x; int h = i & 7;
        float sp = softplusf(zrow[DM_ + CONVDIM_ + i] + dt_bias[h]);
        if (i < 8) dtf[bl*NH_ + h] = sp; else dtb[bl*NH_ + h] = sp;
    }
    __syncthreads();
    if (threadIdx.x < NH_) {
        int h = threadIdx.x;
        float s = Dvec[h];
        const float* fr = fc_D_w + (size_t)h * DM_;
        for (int d = 0; d < DM_; d++) s += sx[d] * fr[d];
        dco[bl*NH_ + h] = s;
    }
}

// ---------------------------------------------------------------------------
// k3: bidirectional scan; y3 = (y_fw + y_bw + dterm) * silu(z)
// grid: B_*HEADS_ = 128 blocks, 64 threads (c)
__global__ void k3_scan(const float* __restrict__ x, const float* __restrict__ zs,
                        const float* __restrict__ Bv, const float* __restrict__ Cv,
                        const float* __restrict__ dtf, const float* __restrict__ dtb,
                        const float* __restrict__ dco, const float* __restrict__ A_log,
                        float* __restrict__ y3) {
    int bh = blockIdx.x; int b = bh >> 3, h = bh & 7;
    int c = threadIdx.x;
    float Ah = -expf(A_log[h]);

    float state = 0.f;
    for (int t = 0; t < G_; t++) {           // forward: writes dterm + y_fw
        int bl = b*G_ + t;
        size_t idx = (size_t)bl*DM_ + h*64 + c;
        float dt = dtf[bl*NH_ + h];
        float a  = expf(dt * Ah);
        float xv = x[idx];
        float val = xv * dco[bl*NH_ + h];    // dterm
        if (t > 0) val += state * Cv[bl - 1];
        y3[idx] = val;
        state = a*state + dt * Bv[bl] * xv;
    }
    state = 0.f;
    for (int s = G_ - 1; s >= 0; s--) {      // backward: adds y_bw, applies silu(z)
        int bl = b*G_ + s;
        size_t idx = (size_t)bl*DM_ + h*64 + c;
        float val = y3[idx];
        if (s < G_ - 1) val += state * Cv[bl + 1];
        val *= zs[idx];
        y3[idx] = val;
        float dt = dtb[bl*NH_ + h];
        float a  = expf(dt * Ah);
        state = a*state + dt * Bv[bl] * x[idx];
    }
}

// ---------------------------------------------------------------------------
// k4: RMSNorm + out_mid = yn @ w_out.T ; also writes outp (output 2)
// grid: B_*G_ blocks, 256 threads
__global__ void k4_rms_wout(const float* __restrict__ y3,
                            const float* __restrict__ norm_w,
                            const float* __restrict__ w_out,
                            float* __restrict__ om, float* __restrict__ out2) {
    int bl = blockIdx.x; int b = bl >> 6, l = bl & 63;
    __shared__ float yn[DM_];
    __shared__ float red[4];
    float ss = 0.f;
    for (int d = threadIdx.x; d < DM_; d += 256) {
        float v = y3[(size_t)bl*DM_ + d];
        yn[d] = v; ss += v*v;
    }
#pragma unroll
    for (int o = 32; o > 0; o >>= 1) ss += __shfl_down(ss, o, 64);
    if ((threadIdx.x & 63) == 0) red[threadIdx.x >> 6] = ss;
    __syncthreads();
    float scale = rsqrtf((red[0]+red[1]+red[2]+red[3]) / (float)DM_ + 1e-5f);
    for (int d = threadIdx.x; d < DM_; d += 256) yn[d] = yn[d] * scale * norm_w[d];
    __syncthreads();
    const float4* y4 = (const float4*)yn;
    for (int dd = threadIdx.x; dd < DM_; dd += 256) {
        const float4* wr = (const float4*)(w_out + (size_t)dd * DM_);
        float s = 0.f;
#pragma unroll 8
        for (int q = 0; q < DM_/4; q++) {
            float4 w4 = wr[q]; float4 uu = y4[q];
            s += w4.x*uu.x + w4.y*uu.y + w4.z*uu.z + w4.w*uu.w;
        }
        om[(size_t)bl*DM_ + dd] = s;
        int h = dd >> 6, c = dd & 63;
        out2[(((b*HEADS_ + h)*G_ + l) << 6) + c] = s;
    }
}

// ---------------------------------------------------------------------------
// k5: P[b, h*64+g, d] = sum_c om[b,g,h*64+c] * to_out_w[d, h*64+c]
// grid: B_*HEADS_ = 128 blocks, 256 threads
__global__ void k5_P(const float* __restrict__ om,
                     const float* __restrict__ to_out_w,
                     float* __restrict__ P) {
    int bh = blockIdx.x; int b = bh >> 3, h = bh & 7;
    __shared__ float a[64][64];   // a[g][c]
    for (int i = threadIdx.x; i < 64*64; i += 256) {
        int g = i >> 6, c = i & 63;
        a[g][c] = om[(size_t)(b*G_ + g)*DM_ + h*64 + c];
    }
    __syncthreads();
    for (int d = threadIdx.x; d < DIM_; d += 256) {
        float w[64];
        const float4* wr = (const float4*)(to_out_w + (size_t)d * DM_ + h*64);
#pragma unroll
        for (int q = 0; q < 16; q++) {
            float4 t = wr[q];
            w[q*4] = t.x; w[q*4+1] = t.y; w[q*4+2] = t.z; w[q*4+3] = t.w;
        }
        for (int g = 0; g < 64; g++) {
            float s = 0.f;
#pragma unroll
            for (int c = 0; c < 64; c++) s += a[g][c] * w[c];
            P[(size_t)(b*512 + h*64 + g)*DIM_ + d] = s;
        }
    }
}

// ---------------------------------------------------------------------------
// k6: out0[b,n,d] = sum_k W[b,n,k]*P[b,k,d] + to_out_b[d]
//     W[b,n,h*64+g] = sw[((b*8+h)*N_+n)*64+g]  (A-tile contiguous per head)
// grid: (8 d-tiles, 49 n-tiles, 16 b), 256 threads; BM=BN=BK=64
__global__ void k6_gemm(const float* __restrict__ sw,
                        const float* __restrict__ P,
                        const float* __restrict__ bias,
                        float* __restrict__ out0) {
    __shared__ float Ast[64][68];   // A transposed: Ast[g][n_local]
    __shared__ float Bs[64][68];    // Bs[k_local][d_local]
    int d0 = blockIdx.x * 64;
    int n0 = blockIdx.y * 64;
    int b  = blockIdx.z;
    int tid = threadIdx.x;
    int tx = tid & 15, ty = tid >> 4;

    float acc[4][4];
#pragma unroll
    for (int i = 0; i < 4; i++)
#pragma unroll
        for (int j = 0; j < 4; j++) acc[i][j] = 0.f;

    for (int h = 0; h < 8; h++) {
        // A tile: contiguous block of sw
        const float* Abase = sw + ((size_t)(b*HEADS_ + h)*N_ + n0) * 64;
        for (int i = tid; i < 1024; i += 256) {
            int nl = i >> 4, gq = i & 15;
            float4 v = make_float4(0.f, 0.f, 0.f, 0.f);
            if (n0 + nl < N_) v = *(const float4*)(Abase + nl*64 + gq*4);
            Ast[gq*4 + 0][nl] = v.x;
            Ast[gq*4 + 1][nl] = v.y;
            Ast[gq*4 + 2][nl] = v.z;
            Ast[gq*4 + 3][nl] = v.w;
        }
        // B tile
        const float* Bbase = P + (size_t)(b*512 + h*64)*DIM_ + d0;
        for (int i = tid; i < 1024; i += 256) {
            int kl = i >> 4, dq = i & 15;
            float4 v = *(const float4*)(Bbase + (size_t)kl*DIM_ + dq*4);
            *(float4*)&Bs[kl][dq*4] = v;
        }
        __syncthreads();
#pragma unroll 8
        for (int k = 0; k < 64; k++) {
            float4 av = *(const float4*)&Ast[k][ty*4];
            float4 bv = *(const float4*)&Bs[k][tx*4];
            float aa[4] = {av.x, av.y, av.z, av.w};
            float bb[4] = {bv.x, bv.y, bv.z, bv.w};
#pragma unroll
            for (int i = 0; i < 4; i++)
#pragma unroll
                for (int j = 0; j < 4; j++) acc[i][j] += aa[i] * bb[j];
        }
        __syncthreads();
    }
    float4 bi = *(const float4*)(bias + d0 + tx*4);
    float bb[4] = {bi.x, bi.y, bi.z, bi.w};
#pragma unroll
    for (int i = 0; i < 4; i++) {
        int n = n0 + ty*4 + i;
        if (n < N_) {
            float4 v = make_float4(acc[i][0]+bb[0], acc[i][1]+bb[1],
                                   acc[i][2]+bb[2], acc[i][3]+bb[3]);
            *(float4*)(out0 + ((size_t)b*N_ + n)*DIM_ + d0 + tx*4) = v;
        }
    }
}

// ---------------------------------------------------------------------------
extern "C" void kernel_launch(void* const* d_in, const int* in_sizes, int n_in,
                              void* d_out, int out_size, void* d_ws, size_t ws_size,
                              hipStream_t stream) {
    const float* st      = (const float*)d_in[0];
    const float* sw      = (const float*)d_in[1];
    const float* w_in    = (const float*)d_in[2];
    const float* conv_w  = (const float*)d_in[3];
    const float* conv_b  = (const float*)d_in[4];
    const float* dt_bias = (const float*)d_in[5];
    const float* A_log   = (const float*)d_in[6];
    const float* Dvec    = (const float*)d_in[7];
    const float* fc_D_w  = (const float*)d_in[8];
    const float* norm_w  = (const float*)d_in[9];
    const float* w_out   = (const float*)d_in[10];
    const float* to_out_w= (const float*)d_in[11];
    const float* to_out_b= (const float*)d_in[12];
    float* out = (float*)d_out;
    float* ws  = (float*)d_ws;

    float* zx  = ws;                          // B*G*DINPROJ = 1,067,008
    float* xb  = zx  + (size_t)B_*G_*DINPROJ_;// B*G*DM
    float* zs  = xb  + (size_t)B_*G_*DM_;
    float* Bv  = zs  + (size_t)B_*G_*DM_;     // B*G
    float* Cv  = Bv  + B_*G_;
    float* dtf = Cv  + B_*G_;                 // B*G*NH
    float* dtb = dtf + B_*G_*NH_;
    float* dco = dtb + B_*G_*NH_;
    float* y3  = dco + B_*G_*NH_;             // B*G*DM
    float* om  = y3  + (size_t)B_*G_*DM_;     // B*G*DM
    float* Pm  = om  + (size_t)B_*G_*DM_;     // B*512*DIM = 4,194,304

    k1_inproj<<<B_*G_, 256, 0, stream>>>(st, w_in, zx);
    k2_conv  <<<B_*G_, 256, 0, stream>>>(zx, conv_w, conv_b, dt_bias, fc_D_w, Dvec,
                                         xb, zs, Bv, Cv, dtf, dtb, dco);
    k3_scan  <<<B_*HEADS_, 64, 0, stream>>>(xb, zs, Bv, Cv, dtf, dtb, dco, A_log, y3);
    k4_rms_wout<<<B_*G_, 256, 0, stream>>>(y3, norm_w, w_out, om, out + OUT2_OFS);
    k5_P     <<<B_*HEADS_, 256, 0, stream>>>(om, to_out_w, Pm);
    dim3 g6(DIM_/64, (N_ + 63)/64, B_);
    k6_gemm  <<<g6, 256, 0, stream>>>(sw, Pm, to_out_b, out + OUT0_OFS);
    hipMemcpyAsync(out + OUT1_OFS, st, (size_t)B_*HEADS_*G_*DH_*sizeof(float),
                   hipMemcpyDeviceToDevice, stream);
}

// Round 2
// 689.138 us; speedup vs baseline: 1.5751x; 1.5751x over previous
//
#include <hip/hip_runtime.h>
#include <math.h>

#define B_ 16
#define HEADS_ 8
#define G_ 64          // == L
#define DH_ 64
#define N_ 3131
#define DM_ 512
#define NH_ 8
#define DINPROJ_ 1042
#define CONVDIM_ 514
#define DIM_ 512

#define OUT0_OFS 0
#define OUT1_OFS (B_*N_*DIM_)
#define OUT2_OFS (B_*N_*DIM_ + B_*HEADS_*G_*DH_)

typedef __attribute__((ext_vector_type(8))) short short8;
typedef __attribute__((ext_vector_type(4))) float f32x4;

__device__ __forceinline__ float siluf(float v){ return v / (1.f + expf(-v)); }
__device__ __forceinline__ float softplusf(float v){ return (v > 20.f) ? v : log1pf(expf(v)); }
__device__ __forceinline__ unsigned short f2bf(float f){
    unsigned int u = __float_as_uint(f);
    unsigned int r = (u + 0x7fffu + ((u >> 16) & 1u)) >> 16;
    return (unsigned short)r;
}

// ---------------------------------------------------------------------------
// k1: zx[bl][j] = sum_d u[bl][d] * w_in[j][d]; u[b*64+l][h*64+c]=st[b][h][l][c]
// fp32 tiled GEMM 64x64x64; A-tile per head is a contiguous 16KB block of st.
// grid (17 j-tiles, 16 b), 256 threads
__global__ void k1_inproj(const float* __restrict__ st,
                          const float* __restrict__ w_in,
                          float* __restrict__ zx) {
    __shared__ float Ast[64][68];   // [c][l]
    __shared__ float Bs[64][68];    // [c][jl]
    int j0 = blockIdx.x * 64;
    int b  = blockIdx.y;
    int tid = threadIdx.x, tx = tid & 15, ty = tid >> 4;
    float acc[4][4];
#pragma unroll
    for (int i = 0; i < 4; i++)
#pragma unroll
        for (int j = 0; j < 4; j++) acc[i][j] = 0.f;

    for (int h = 0; h < 8; h++) {
        const float* Ab = st + ((size_t)(b*8 + h) * 64) * 64;   // [l][c] 64x64
        for (int i = tid; i < 1024; i += 256) {
            int l = i >> 4, cq = i & 15;
            float4 v = *(const float4*)(Ab + l*64 + cq*4);
            Ast[cq*4+0][l] = v.x; Ast[cq*4+1][l] = v.y;
            Ast[cq*4+2][l] = v.z; Ast[cq*4+3][l] = v.w;
        }
        for (int i = tid; i < 1024; i += 256) {
            int jl = i >> 4, cq = i & 15;
            int j = j0 + jl;
            float4 v = make_float4(0.f,0.f,0.f,0.f);
            if (j < DINPROJ_) v = *(const float4*)(w_in + (size_t)j*DM_ + h*64 + cq*4);
            Bs[cq*4+0][jl] = v.x; Bs[cq*4+1][jl] = v.y;
            Bs[cq*4+2][jl] = v.z; Bs[cq*4+3][jl] = v.w;
        }
        __syncthreads();
#pragma unroll 8
        for (int k = 0; k < 64; k++) {
            float4 av = *(const float4*)&Ast[k][ty*4];
            float4 bv = *(const float4*)&Bs[k][tx*4];
            float aa[4] = {av.x, av.y, av.z, av.w};
            float bb[4] = {bv.x, bv.y, bv.z, bv.w};
#pragma unroll
            for (int i = 0; i < 4; i++)
#pragma unroll
                for (int j = 0; j < 4; j++) acc[i][j] += aa[i]*bb[j];
        }
        __syncthreads();
    }
#pragma unroll
    for (int i = 0; i < 4; i++) {
        int bl = b*64 + ty*4 + i;
#pragma unroll
        for (int j = 0; j < 4; j++) {
            int jj = j0 + tx*4 + j;
            if (jj < DINPROJ_) zx[(size_t)bl*DINPROJ_ + jj] = acc[i][j];
        }
    }
}

// ---------------------------------------------------------------------------
// k2: conv3 + silu -> x, Bv, Cv ; silu(z) ; softplus dt fw/bw ; dcoef
__global__ void k2_conv(const float* __restrict__ zx,
                        const float* __restrict__ conv_w,
                        const float* __restrict__ conv_b,
                        const float* __restrict__ dt_bias,
                        const float* __restrict__ fc_D_w,
                        const float* __restrict__ Dvec,
                        float* __restrict__ x, float* __restrict__ zs,
                        float* __restrict__ Bv, float* __restrict__ Cv,
                        float* __restrict__ dtf, float* __restrict__ dtb,
                        float* __restrict__ dco) {
    int bl = blockIdx.x; int b = bl >> 6, l = bl & 63;
    __shared__ float sx[DM_];
    const float* zrow = zx + (size_t)bl * DINPROJ_;

    for (int ch = threadIdx.x; ch < CONVDIM_; ch += 256) {
        float v = conv_b[ch];
#pragma unroll
        for (int k = 0; k < 3; k++) {
            int t = l - 2 + k;
            if (t >= 0) v += conv_w[ch*3 + k] * zx[(size_t)(b*G_ + t) * DINPROJ_ + DM_ + ch];
        }
        float sv = siluf(v);
        if (ch < DM_)      { x[(size_t)bl*DM_ + ch] = sv; sx[ch] = sv; }
        else if (ch == DM_){ Bv[bl] = sv; }
        else               { Cv[bl] = sv; }
    }
    for (int d = threadIdx.x; d < DM_; d += 256) {
        zs[(size_t)bl*DM_ + d] = siluf(zrow[d]);
    }
    if (threadIdx.x < 16) {
        int i = threadIdx.x; int h = i & 7;
        float sp = softplusf(zrow[DM_ + CONVDIM_ + i] + dt_bias[h]);
        if (i < 8) dtf[bl*NH_ + h] = sp; else dtb[bl*NH_ + h] = sp;
    }
    __syncthreads();
    if (threadIdx.x < NH_) {
        int h = threadIdx.x;
        float s = Dvec[h];
        const float* fr = fc_D_w + (size_t)h * DM_;
        for (int d = 0; d < DM_; d++) s += sx[d] * fr[d];
        dco[bl*NH_ + h] = s;
    }
}

// ---------------------------------------------------------------------------
// k3: bidirectional scan; y3 = (y_fw + y_bw + dterm) * silu(z)
__global__ void k3_scan(const float* __restrict__ x, const float* __restrict__ zs,
                        const float* __restrict__ Bv, const float* __restrict__ Cv,
                        const float* __restrict__ dtf, const float* __restrict__ dtb,
                        const float* __restrict__ dco, const float* __restrict__ A_log,
                        float* __restrict__ y3) {
    int bh = blockIdx.x; int b = bh >> 3, h = bh & 7;
    int c = threadIdx.x;
    float Ah = -expf(A_log[h]);

    float state = 0.f;
    for (int t = 0; t < G_; t++) {
        int bl = b*G_ + t;
        size_t idx = (size_t)bl*DM_ + h*64 + c;
        float dt = dtf[bl*NH_ + h];
        float a  = expf(dt * Ah);
        float xv = x[idx];
        float val = xv * dco[bl*NH_ + h];
        if (t > 0) val += state * Cv[bl - 1];
        y3[idx] = val;
        state = a*state + dt * Bv[bl] * xv;
    }
    state = 0.f;
    for (int s = G_ - 1; s >= 0; s--) {
        int bl = b*G_ + s;
        size_t idx = (size_t)bl*DM_ + h*64 + c;
        float val = y3[idx];
        if (s < G_ - 1) val += state * Cv[bl + 1];
        val *= zs[idx];
        y3[idx] = val;
        float dt = dtb[bl*NH_ + h];
        float a  = expf(dt * Ah);
        state = a*state + dt * Bv[bl] * x[idx];
    }
}

// ---------------------------------------------------------------------------
// k4a: RMSNorm only -> yn (fp32)
__global__ void k4a_rms(const float* __restrict__ y3,
                        const float* __restrict__ norm_w,
                        float* __restrict__ yn) {
    int bl = blockIdx.x;
    __shared__ float red[4];
    float vv[2]; float ss = 0.f;
#pragma unroll
    for (int r = 0; r < 2; r++) {
        float v = y3[(size_t)bl*DM_ + threadIdx.x + r*256];
        vv[r] = v; ss += v*v;
    }
#pragma unroll
    for (int o = 32; o > 0; o >>= 1) ss += __shfl_down(ss, o, 64);
    if ((threadIdx.x & 63) == 0) red[threadIdx.x >> 6] = ss;
    __syncthreads();
    float scale = rsqrtf((red[0]+red[1]+red[2]+red[3]) / (float)DM_ + 1e-5f);
#pragma unroll
    for (int r = 0; r < 2; r++) {
        int d = threadIdx.x + r*256;
        yn[(size_t)bl*DM_ + d] = vv[r] * scale * norm_w[d];
    }
}

// ---------------------------------------------------------------------------
// k4b: om[bl][j] = sum_d yn[bl][d]*w_out[j][d]; also out2[b][h][l][c] (h=jtile)
// grid (8 j-tiles, 16 b), 256 threads; fp32 64x64x64 tiles
__global__ void k4b_wout(const float* __restrict__ yn,
                         const float* __restrict__ w_out,
                         float* __restrict__ om, float* __restrict__ out2) {
    __shared__ float Ast[64][68];   // [kd][l]
    __shared__ float Bs[64][68];    // [kd][jl]
    int j0 = blockIdx.x * 64;
    int b  = blockIdx.y;
    int tid = threadIdx.x, tx = tid & 15, ty = tid >> 4;
    float acc[4][4];
#pragma unroll
    for (int i = 0; i < 4; i++)
#pragma unroll
        for (int j = 0; j < 4; j++) acc[i][j] = 0.f;

    for (int kt = 0; kt < 8; kt++) {
        const float* Ab = yn + (size_t)(b*64)*DM_ + kt*64;   // rows l, stride 512
        for (int i = tid; i < 1024; i += 256) {
            int l = i >> 4, cq = i & 15;
            float4 v = *(const float4*)(Ab + (size_t)l*DM_ + cq*4);
            Ast[cq*4+0][l] = v.x; Ast[cq*4+1][l] = v.y;
            Ast[cq*4+2][l] = v.z; Ast[cq*4+3][l] = v.w;
        }
        for (int i = tid; i < 1024; i += 256) {
            int jl = i >> 4, cq = i & 15;
            float4 v = *(const float4*)(w_out + (size_t)(j0 + jl)*DM_ + kt*64 + cq*4);
            Bs[cq*4+0][jl] = v.x; Bs[cq*4+1][jl] = v.y;
            Bs[cq*4+2][jl] = v.z; Bs[cq*4+3][jl] = v.w;
        }
        __syncthreads();
#pragma unroll 8
        for (int k = 0; k < 64; k++) {
            float4 av = *(const float4*)&Ast[k][ty*4];
            float4 bv = *(const float4*)&Bs[k][tx*4];
            float aa[4] = {av.x, av.y, av.z, av.w};
            float bb[4] = {bv.x, bv.y, bv.z, bv.w};
#pragma unroll
            for (int i = 0; i < 4; i++)
#pragma unroll
                for (int j = 0; j < 4; j++) acc[i][j] += aa[i]*bb[j];
        }
        __syncthreads();
    }
#pragma unroll
    for (int i = 0; i < 4; i++) {
        int l = ty*4 + i, bl = b*64 + l;
        float4 v = make_float4(acc[i][0], acc[i][1], acc[i][2], acc[i][3]);
        *(float4*)(om + (size_t)bl*DM_ + j0 + tx*4) = v;
        // out2[b][h=blockIdx.x][l][c], c = tx*4..
        *(float4*)(out2 + (((size_t)(b*8 + blockIdx.x)*64 + l) << 6) + tx*4) = v;
    }
}

// ---------------------------------------------------------------------------
// k5: P[b][k=h*64+g][d] = sum_c om[b,g,h*64+c] * to_out_w[d, h*64+c]  (fp32)
__global__ void k5_P(const float* __restrict__ om,
                     const float* __restrict__ to_out_w,
                     float* __restrict__ P) {
    int bh = blockIdx.x; int b = bh >> 3, h = bh & 7;
    __shared__ float a[64][64];   // a[g][c]
    for (int i = threadIdx.x; i < 64*64; i += 256) {
        int g = i >> 6, c = i & 63;
        a[g][c] = om[(size_t)(b*G_ + g)*DM_ + h*64 + c];
    }
    __syncthreads();
    for (int d = threadIdx.x; d < DIM_; d += 256) {
        float w[64];
        const float4* wr = (const float4*)(to_out_w + (size_t)d * DM_ + h*64);
#pragma unroll
        for (int q = 0; q < 16; q++) {
            float4 t = wr[q];
            w[q*4] = t.x; w[q*4+1] = t.y; w[q*4+2] = t.z; w[q*4+3] = t.w;
        }
        for (int g = 0; g < 64; g++) {
            float s = 0.f;
#pragma unroll
            for (int c = 0; c < 64; c++) s += a[g][c] * w[c];
            P[(size_t)(b*512 + h*64 + g)*DIM_ + d] = s;
        }
    }
}

// ---------------------------------------------------------------------------
// k5b: Pbf[b][d][k] = bf16(P[b][k][d])  (transpose so GEMM B is k-contiguous)
// grid (8 k-tiles, 8 d-tiles, 16 b)
__global__ void k5b_transpose(const float* __restrict__ P,
                              unsigned short* __restrict__ Pbf) {
    int k0 = blockIdx.x * 64, d0 = blockIdx.y * 64, b = blockIdx.z;
    __shared__ float t[64][65];
    for (int i = threadIdx.x; i < 4096; i += 256) {
        int k = i >> 6, d = i & 63;
        t[k][d] = P[((size_t)(b*512) + k0 + k)*DIM_ + d0 + d];
    }
    __syncthreads();
    for (int i = threadIdx.x; i < 4096; i += 256) {
        int d = i >> 6, k = i & 63;
        Pbf[((size_t)(b*512) + d0 + d)*512 + k0 + k] = f2bf(t[k][d]);
    }
}

// ---------------------------------------------------------------------------
// k6: out0[b][n][d] = sum_k W[b][n][k]*P[b][k][d] + bias[d], bf16 MFMA.
// A: sw (fp32) converted in-register -> LDS [n][k] bf16 (per head, the global
//    A-tile is one contiguous 32KB block).
// B: Pbf [b][d][k] bf16 staged via global_load_lds width-16 -> LDS [d][k].
// 128x128 tile, BK=64, 4 waves (2x2 of 64x64), mfma_f32_16x16x32_bf16.
// grid (4 d-tiles, 25 n-tiles, 16 b)
__global__ __launch_bounds__(256) void k6_gemm(
        const float* __restrict__ sw,
        const unsigned short* __restrict__ Pbf,
        const float* __restrict__ bias,
        float* __restrict__ out0) {
    __shared__ unsigned short As[128*64];   // [n][k] 16 KB
    __shared__ unsigned short Bs[128*64];   // [d][k] 16 KB
    int d0 = blockIdx.x * 128;
    int n0 = blockIdx.y * 128;
    int b  = blockIdx.z;
    int tid = threadIdx.x;
    int lane = tid & 63, wid = tid >> 6;
    int wm = wid & 1, wn = wid >> 1;
    int quad = lane >> 4, m16 = lane & 15;

    f32x4 acc[4][4] = {};

    for (int kt = 0; kt < 8; kt++) {
        // ---- stage A: contiguous fp32 block -> bf16 LDS [n][k]
        const float* Ab = sw + ((size_t)(b*8 + kt) * N_ + n0) * 64;
#pragma unroll
        for (int r = 0; r < 8; r++) {
            int f = r*256 + tid;          // float4 index, 2048 total
            int nl = f >> 4;              // local row 0..127
            float4 v = make_float4(0.f,0.f,0.f,0.f);
            if (n0 + nl < N_) v = ((const float4*)Ab)[f];
            ushort4 o;
            o.x = f2bf(v.x); o.y = f2bf(v.y); o.z = f2bf(v.z); o.w = f2bf(v.w);
            *(ushort4*)&As[f*4] = o;
        }
        // ---- stage B: global_load_lds, 16B/lane; rows d0..d0+127, 128B slice,
        //      row stride 1024B. chunk c = 8 rows = 1024B of LDS.
        const unsigned short* Bb = Pbf + ((size_t)(b*512) + d0)*512 + kt*64;
#pragma unroll
        for (int c = wid; c < 16; c += 4) {
            const unsigned short* gp = Bb + (size_t)(c*8 + (lane >> 3))*512 + (lane & 7)*8;
            __builtin_amdgcn_global_load_lds(
                (const __attribute__((address_space(1))) unsigned int*)gp,
                (__attribute__((address_space(3))) unsigned int*)&Bs[c*512],
                16, 0, 0);
        }
        __syncthreads();
        // ---- compute: 2 k-steps of 32
#pragma unroll
        for (int ks = 0; ks < 2; ks++) {
            short8 av[4], bv[4];
#pragma unroll
            for (int mt = 0; mt < 4; mt++)
                av[mt] = *(short8*)&As[(wm*64 + mt*16 + m16)*64 + ks*32 + quad*8];
#pragma unroll
            for (int nt = 0; nt < 4; nt++)
                bv[nt] = *(short8*)&Bs[(wn*64 + nt*16 + m16)*64 + ks*32 + quad*8];
#pragma unroll
            for (int mt = 0; mt < 4; mt++)
#pragma unroll
                for (int nt = 0; nt < 4; nt++)
                    acc[mt][nt] = __builtin_amdgcn_mfma_f32_16x16x32_bf16(
                        av[mt], bv[nt], acc[mt][nt], 0, 0, 0);
        }
        __syncthreads();
    }
    // ---- epilogue: D[row=n][col=d], col=lane&15, row=quad*4+reg
#pragma unroll
    for (int nt = 0; nt < 4; nt++) {
        int dcol = d0 + wn*64 + nt*16 + m16;
        float bval = bias[dcol];
#pragma unroll
        for (int mt = 0; mt < 4; mt++) {
#pragma unroll
            for (int r = 0; r < 4; r++) {
                int n = n0 + wm*64 + mt*16 + quad*4 + r;
                if (n < N_)
                    out0[((size_t)b*N_ + n)*DIM_ + dcol] = acc[mt][nt][r] + bval;
            }
        }
    }
}

// ---------------------------------------------------------------------------
extern "C" void kernel_launch(void* const* d_in, const int* in_sizes, int n_in,
                              void* d_out, int out_size, void* d_ws, size_t ws_size,
                              hipStream_t stream) {
    const float* st      = (const float*)d_in[0];
    const float* sw      = (const float*)d_in[1];
    const float* w_in    = (const float*)d_in[2];
    const float* conv_w  = (const float*)d_in[3];
    const float* conv_b  = (const float*)d_in[4];
    const float* dt_bias = (const float*)d_in[5];
    const float* A_log   = (const float*)d_in[6];
    const float* Dvec    = (const float*)d_in[7];
    const float* fc_D_w  = (const float*)d_in[8];
    const float* norm_w  = (const float*)d_in[9];
    const float* w_out   = (const float*)d_in[10];
    const float* to_out_w= (const float*)d_in[11];
    const float* to_out_b= (const float*)d_in[12];
    float* out = (float*)d_out;
    float* ws  = (float*)d_ws;

    float* zx  = ws;                            // 1,067,008
    float* xb  = zx  + (size_t)B_*G_*DINPROJ_;  // 524,288
    float* zs  = xb  + (size_t)B_*G_*DM_;       // 524,288
    float* Bv  = zs  + (size_t)B_*G_*DM_;       // 1024
    float* Cv  = Bv  + B_*G_;                   // 1024
    float* dtf = Cv  + B_*G_;                   // 8192
    float* dtb = dtf + B_*G_*NH_;
    float* dco = dtb + B_*G_*NH_;
    float* y3  = dco + B_*G_*NH_;               // 524,288
    float* om  = y3;                            // alias: y3 dead after k4a
    float* yn  = y3  + (size_t)B_*G_*DM_;       // 524,288
    float* Pm  = yn  + (size_t)B_*G_*DM_;       // 4,194,304
    // Pbf aliases zx+xb+zs (all dead after k3): needs 2,097,152 float-slots
    unsigned short* Pbf = (unsigned short*)ws;

    dim3 g1(17, 16);
    k1_inproj<<<g1, 256, 0, stream>>>(st, w_in, zx);
    k2_conv  <<<B_*G_, 256, 0, stream>>>(zx, conv_w, conv_b, dt_bias, fc_D_w, Dvec,
                                         xb, zs, Bv, Cv, dtf, dtb, dco);
    k3_scan  <<<B_*HEADS_, 64, 0, stream>>>(xb, zs, Bv, Cv, dtf, dtb, dco, A_log, y3);
    k4a_rms  <<<B_*G_, 256, 0, stream>>>(y3, norm_w, yn);
    dim3 g4(8, 16);
    k4b_wout <<<g4, 256, 0, stream>>>(yn, w_out, om, out + OUT2_OFS);
    k5_P     <<<B_*HEADS_, 256, 0, stream>>>(om, to_out_w, Pm);
    dim3 g5b(8, 8, 16);
    k5b_transpose<<<g5b, 256, 0, stream>>>(Pm, Pbf);
    dim3 g6(4, 25, 16);
    k6_gemm  <<<g6, 256, 0, stream>>>(sw, Pbf, to_out_b, out + OUT0_OFS);
    hipMemcpyAsync(out + OUT1_OFS, st, (size_t)B_*HEADS_*G_*DH_*sizeof(float),
                   hipMemcpyDeviceToDevice, stream);
}

// Round 3
// 627.016 us; speedup vs baseline: 1.7312x; 1.0991x over previous
//
#include <hip/hip_runtime.h>
#include <math.h>

#define B_ 16
#define HEADS_ 8
#define G_ 64          // == L
#define DH_ 64
#define N_ 3131
#define DM_ 512
#define NH_ 8
#define DINPROJ_ 1042
#define CONVDIM_ 514
#define DIM_ 512

#define OUT0_OFS 0
#define OUT1_OFS (B_*N_*DIM_)
#define OUT2_OFS (B_*N_*DIM_ + B_*HEADS_*G_*DH_)

#define SW_ELEMS (B_*HEADS_*N_*64)   // 25,649,152

typedef __attribute__((ext_vector_type(8))) short short8;
typedef __attribute__((ext_vector_type(4))) float f32x4;

__device__ __forceinline__ float siluf(float v){ return v / (1.f + expf(-v)); }
__device__ __forceinline__ float softplusf(float v){ return (v > 20.f) ? v : log1pf(expf(v)); }
__device__ __forceinline__ unsigned short f2bf(float f){
    unsigned int u = __float_as_uint(f);
    unsigned int r = (u + 0x7fffu + ((u >> 16) & 1u)) >> 16;
    return (unsigned short)r;
}

// ---------------------------------------------------------------------------
// k0: sw fp32 -> bf16 (contiguous). 8 elems/thread.
__global__ void k0_cvt(const float* __restrict__ sw, unsigned short* __restrict__ swb) {
    int i = blockIdx.x * 256 + threadIdx.x;       // group of 8
    const float4* p = (const float4*)(sw + (size_t)i * 8);
    float4 v0 = p[0], v1 = p[1];
    short8 o;
    o[0]=f2bf(v0.x); o[1]=f2bf(v0.y); o[2]=f2bf(v0.z); o[3]=f2bf(v0.w);
    o[4]=f2bf(v1.x); o[5]=f2bf(v1.y); o[6]=f2bf(v1.z); o[7]=f2bf(v1.w);
    *(short8*)(swb + (size_t)i * 8) = o;
}

// ---------------------------------------------------------------------------
// k1: zx[bl][j] = sum_d u[bl][d] * w_in[j][d]
__global__ void k1_inproj(const float* __restrict__ st,
                          const float* __restrict__ w_in,
                          float* __restrict__ zx) {
    __shared__ float Ast[64][68];   // [c][l]
    __shared__ float Bs[64][68];    // [c][jl]
    int j0 = blockIdx.x * 64;
    int b  = blockIdx.y;
    int tid = threadIdx.x, tx = tid & 15, ty = tid >> 4;
    float acc[4][4];
#pragma unroll
    for (int i = 0; i < 4; i++)
#pragma unroll
        for (int j = 0; j < 4; j++) acc[i][j] = 0.f;

    for (int h = 0; h < 8; h++) {
        const float* Ab = st + ((size_t)(b*8 + h) * 64) * 64;
        for (int i = tid; i < 1024; i += 256) {
            int l = i >> 4, cq = i & 15;
            float4 v = *(const float4*)(Ab + l*64 + cq*4);
            Ast[cq*4+0][l] = v.x; Ast[cq*4+1][l] = v.y;
            Ast[cq*4+2][l] = v.z; Ast[cq*4+3][l] = v.w;
        }
        for (int i = tid; i < 1024; i += 256) {
            int jl = i >> 4, cq = i & 15;
            int j = j0 + jl;
            float4 v = make_float4(0.f,0.f,0.f,0.f);
            if (j < DINPROJ_) v = *(const float4*)(w_in + (size_t)j*DM_ + h*64 + cq*4);
            Bs[cq*4+0][jl] = v.x; Bs[cq*4+1][jl] = v.y;
            Bs[cq*4+2][jl] = v.z; Bs[cq*4+3][jl] = v.w;
        }
        __syncthreads();
#pragma unroll 8
        for (int k = 0; k < 64; k++) {
            float4 av = *(const float4*)&Ast[k][ty*4];
            float4 bv = *(const float4*)&Bs[k][tx*4];
            float aa[4] = {av.x, av.y, av.z, av.w};
            float bb[4] = {bv.x, bv.y, bv.z, bv.w};
#pragma unroll
            for (int i = 0; i < 4; i++)
#pragma unroll
                for (int j = 0; j < 4; j++) acc[i][j] += aa[i]*bb[j];
        }
        __syncthreads();
    }
#pragma unroll
    for (int i = 0; i < 4; i++) {
        int bl = b*64 + ty*4 + i;
#pragma unroll
        for (int j = 0; j < 4; j++) {
            int jj = j0 + tx*4 + j;
            if (jj < DINPROJ_) zx[(size_t)bl*DINPROJ_ + jj] = acc[i][j];
        }
    }
}

// ---------------------------------------------------------------------------
// k2: conv3+silu -> x,(B,C); silu(z); scan tables a=exp(dt*A), bb=dt*Bv; dcoef
__global__ void k2_conv(const float* __restrict__ zx,
                        const float* __restrict__ conv_w,
                        const float* __restrict__ conv_b,
                        const float* __restrict__ dt_bias,
                        const float* __restrict__ A_log,
                        const float* __restrict__ fc_D_w,
                        const float* __restrict__ Dvec,
                        float* __restrict__ x, float* __restrict__ zs,
                        float* __restrict__ Cv, float* __restrict__ tblf,
                        float* __restrict__ dco) {
    int bl = blockIdx.x; int b = bl >> 6, l = bl & 63;
    __shared__ float sx[DM_];
    __shared__ float sBv;
    const float* zrow = zx + (size_t)bl * DINPROJ_;

    for (int ch = threadIdx.x; ch < CONVDIM_; ch += 256) {
        float v = conv_b[ch];
#pragma unroll
        for (int k = 0; k < 3; k++) {
            int t = l - 2 + k;
            if (t >= 0) v += conv_w[ch*3 + k] * zx[(size_t)(b*G_ + t) * DINPROJ_ + DM_ + ch];
        }
        float sv = siluf(v);
        if (ch < DM_)      { x[(size_t)bl*DM_ + ch] = sv; sx[ch] = sv; }
        else if (ch == DM_){ sBv = sv; }
        else               { Cv[bl] = sv; }
    }
    for (int d = threadIdx.x; d < DM_; d += 256) {
        zs[(size_t)bl*DM_ + d] = siluf(zrow[d]);
    }
    __syncthreads();
    if (threadIdx.x < 16) {
        int i = threadIdx.x; int h = i & 7;
        float dt = softplusf(zrow[DM_ + CONVDIM_ + i] + dt_bias[h]);
        float Ah = -expf(A_log[h]);
        float a  = expf(dt * Ah);
        float bb = dt * sBv;
        float* t4 = tblf + ((size_t)bl*NH_ + h)*4;
        if (i < 8) { t4[0] = a; t4[1] = bb; }
        else       { t4[2] = a; t4[3] = bb; }
    }
    if (threadIdx.x >= 64 && threadIdx.x < 64 + NH_) {
        int h = threadIdx.x - 64;
        float s = Dvec[h];
        const float* fr = fc_D_w + (size_t)h * DM_;
        for (int d = 0; d < DM_; d++) s += sx[d] * fr[d];
        dco[bl*NH_ + h] = s;
    }
}

// ---------------------------------------------------------------------------
// k3: directional scan. dir=0: yfw = dterm + y_fw ; dir=1: ybw = y_bw
// grid (B_*HEADS_, 2), 64 threads
__global__ void k3_scan(const float* __restrict__ x, const float* __restrict__ Cv,
                        const float* __restrict__ tblf, const float* __restrict__ dco,
                        float* __restrict__ yfw, float* __restrict__ ybw) {
    int bh = blockIdx.x; int b = bh >> 3, h = bh & 7;
    int dir = blockIdx.y;
    int c = threadIdx.x;
    __shared__ float sA[64], sB[64], sC[64], sD[64];
    {
        int bl = b*64 + c;
        const float* t4 = tblf + ((size_t)bl*NH_ + h)*4;
        sA[c] = dir ? t4[2] : t4[0];
        sB[c] = dir ? t4[3] : t4[1];
        sC[c] = Cv[bl];
        sD[c] = dco[bl*NH_ + h];
    }
    __syncthreads();
    const float* xr = x + (size_t)(b*64)*DM_ + h*64 + c;
    if (dir == 0) {
        float* yw = yfw + (size_t)(b*64)*DM_ + h*64 + c;
        float state = 0.f;
        float xv = xr[0];
#pragma unroll 4
        for (int t = 0; t < 64; t++) {
            float xn = (t < 63) ? xr[(t+1)*DM_] : 0.f;
            float val = xv * sD[t];
            if (t > 0) val += state * sC[t-1];
            yw[t*DM_] = val;
            state = sA[t]*state + sB[t]*xv;
            xv = xn;
        }
    } else {
        float* yw = ybw + (size_t)(b*64)*DM_ + h*64 + c;
        float state = 0.f;
        float xv = xr[63*DM_];
#pragma unroll 4
        for (int s = 63; s >= 0; s--) {
            float xn = (s > 0) ? xr[(s-1)*DM_] : 0.f;
            float val = (s < 63) ? state * sC[s+1] : 0.f;
            yw[s*DM_] = val;
            state = sA[s]*state + sB[s]*xv;
            xv = xn;
        }
    }
}

// ---------------------------------------------------------------------------
// k4a: y = (yfw+ybw)*zs ; RMSNorm -> yn
__global__ void k4a_rms(const float* __restrict__ yfw, const float* __restrict__ ybw,
                        const float* __restrict__ zs, const float* __restrict__ norm_w,
                        float* __restrict__ yn) {
    int bl = blockIdx.x;
    __shared__ float red[4];
    float vv[2]; float ss = 0.f;
#pragma unroll
    for (int r = 0; r < 2; r++) {
        size_t i = (size_t)bl*DM_ + threadIdx.x + r*256;
        float v = (yfw[i] + ybw[i]) * zs[i];
        vv[r] = v; ss += v*v;
    }
#pragma unroll
    for (int o = 32; o > 0; o >>= 1) ss += __shfl_down(ss, o, 64);
    if ((threadIdx.x & 63) == 0) red[threadIdx.x >> 6] = ss;
    __syncthreads();
    float scale = rsqrtf((red[0]+red[1]+red[2]+red[3]) / (float)DM_ + 1e-5f);
#pragma unroll
    for (int r = 0; r < 2; r++) {
        int d = threadIdx.x + r*256;
        yn[(size_t)bl*DM_ + d] = vv[r] * scale * norm_w[d];
    }
}

// ---------------------------------------------------------------------------
// k4b: om[bl][j] = sum_d yn[bl][d]*w_out[j][d]; also out2
__global__ void k4b_wout(const float* __restrict__ yn,
                         const float* __restrict__ w_out,
                         float* __restrict__ om, float* __restrict__ out2) {
    __shared__ float Ast[64][68];
    __shared__ float Bs[64][68];
    int j0 = blockIdx.x * 64;
    int b  = blockIdx.y;
    int tid = threadIdx.x, tx = tid & 15, ty = tid >> 4;
    float acc[4][4];
#pragma unroll
    for (int i = 0; i < 4; i++)
#pragma unroll
        for (int j = 0; j < 4; j++) acc[i][j] = 0.f;

    for (int kt = 0; kt < 8; kt++) {
        const float* Ab = yn + (size_t)(b*64)*DM_ + kt*64;
        for (int i = tid; i < 1024; i += 256) {
            int l = i >> 4, cq = i & 15;
            float4 v = *(const float4*)(Ab + (size_t)l*DM_ + cq*4);
            Ast[cq*4+0][l] = v.x; Ast[cq*4+1][l] = v.y;
            Ast[cq*4+2][l] = v.z; Ast[cq*4+3][l] = v.w;
        }
        for (int i = tid; i < 1024; i += 256) {
            int jl = i >> 4, cq = i & 15;
            float4 v = *(const float4*)(w_out + (size_t)(j0 + jl)*DM_ + kt*64 + cq*4);
            Bs[cq*4+0][jl] = v.x; Bs[cq*4+1][jl] = v.y;
            Bs[cq*4+2][jl] = v.z; Bs[cq*4+3][jl] = v.w;
        }
        __syncthreads();
#pragma unroll 8
        for (int k = 0; k < 64; k++) {
            float4 av = *(const float4*)&Ast[k][ty*4];
            float4 bv = *(const float4*)&Bs[k][tx*4];
            float aa[4] = {av.x, av.y, av.z, av.w};
            float bb[4] = {bv.x, bv.y, bv.z, bv.w};
#pragma unroll
            for (int i = 0; i < 4; i++)
#pragma unroll
                for (int j = 0; j < 4; j++) acc[i][j] += aa[i]*bb[j];
        }
        __syncthreads();
    }
#pragma unroll
    for (int i = 0; i < 4; i++) {
        int l = ty*4 + i, bl = b*64 + l;
        float4 v = make_float4(acc[i][0], acc[i][1], acc[i][2], acc[i][3]);
        *(float4*)(om + (size_t)bl*DM_ + j0 + tx*4) = v;
        *(float4*)(out2 + (((size_t)(b*8 + blockIdx.x)*64 + l) << 6) + tx*4) = v;
    }
}

// ---------------------------------------------------------------------------
// k5: Pbf[b][d][h*64+g] = bf16( sum_c om[b,g,h*64+c] * to_out_w[d,h*64+c] )
// transposed + bf16 directly; each thread writes contiguous 128B rows.
__global__ void k5_P(const float* __restrict__ om,
                     const float* __restrict__ to_out_w,
                     unsigned short* __restrict__ Pbf) {
    int bh = blockIdx.x; int b = bh >> 3, h = bh & 7;
    __shared__ float a[64][64];   // a[g][c]
    for (int i = threadIdx.x; i < 64*64; i += 256) {
        int g = i >> 6, c = i & 63;
        a[g][c] = om[(size_t)(b*G_ + g)*DM_ + h*64 + c];
    }
    __syncthreads();
    for (int d = threadIdx.x; d < DIM_; d += 256) {
        float w[64];
        const float4* wr = (const float4*)(to_out_w + (size_t)d * DM_ + h*64);
#pragma unroll
        for (int q = 0; q < 16; q++) {
            float4 t = wr[q];
            w[q*4] = t.x; w[q*4+1] = t.y; w[q*4+2] = t.z; w[q*4+3] = t.w;
        }
        unsigned short* orow = Pbf + ((size_t)(b*512) + d)*512 + h*64;
        for (int gq = 0; gq < 8; gq++) {
            short8 o;
#pragma unroll
            for (int j = 0; j < 8; j++) {
                int g = gq*8 + j;
                float s = 0.f;
#pragma unroll
                for (int c = 0; c < 64; c++) s += a[g][c] * w[c];
                o[j] = (short)f2bf(s);
            }
            *(short8*)(orow + gq*8) = o;
        }
    }
}

// ---------------------------------------------------------------------------
// k6 (async path): out0 = sw @ P + bias, bf16 MFMA, both operands via
// global_load_lds width-16. 128x128 tile, BK=64, 4 waves.
__global__ __launch_bounds__(256) void k6_bf(
        const unsigned short* __restrict__ swb,
        const unsigned short* __restrict__ Pbf,
        const float* __restrict__ bias,
        float* __restrict__ out0) {
    __shared__ unsigned short As[128*64];   // [n][k] 16 KB
    __shared__ unsigned short Bs[128*64];   // [d][k] 16 KB
    int d0 = blockIdx.x * 128;
    int n0 = blockIdx.y * 128;
    int b  = blockIdx.z;
    int tid = threadIdx.x;
    int lane = tid & 63, wid = tid >> 6;
    int wm = wid & 1, wn = wid >> 1;
    int quad = lane >> 4, m16 = lane & 15;

    f32x4 acc[4][4] = {};

    for (int kt = 0; kt < 8; kt++) {
        // A: 16 KB contiguous (rows n, 64 k each); OOB rows read pad, masked at store
        const unsigned short* Ab = swb + ((size_t)(b*8 + kt) * N_ + n0) * 64;
#pragma unroll
        for (int c = wid; c < 16; c += 4) {
            __builtin_amdgcn_global_load_lds(
                (const __attribute__((address_space(1))) unsigned int*)(Ab + c*512 + lane*8),
                (__attribute__((address_space(3))) unsigned int*)&As[c*512],
                16, 0, 0);
        }
        // B: rows d0..d0+127, 128B slices, row stride 1024B
        const unsigned short* Bb = Pbf + ((size_t)(b*512) + d0)*512 + kt*64;
#pragma unroll
        for (int c = wid; c < 16; c += 4) {
            const unsigned short* gp = Bb + (size_t)(c*8 + (lane >> 3))*512 + (lane & 7)*8;
            __builtin_amdgcn_global_load_lds(
                (const __attribute__((address_space(1))) unsigned int*)gp,
                (__attribute__((address_space(3))) unsigned int*)&Bs[c*512],
                16, 0, 0);
        }
        __syncthreads();
#pragma unroll
        for (int ks = 0; ks < 2; ks++) {
            short8 av[4], bv[4];
#pragma unroll
            for (int mt = 0; mt < 4; mt++)
                av[mt] = *(short8*)&As[(wm*64 + mt*16 + m16)*64 + ks*32 + quad*8];
#pragma unroll
            for (int nt = 0; nt < 4; nt++)
                bv[nt] = *(short8*)&Bs[(wn*64 + nt*16 + m16)*64 + ks*32 + quad*8];
#pragma unroll
            for (int mt = 0; mt < 4; mt++)
#pragma unroll
                for (int nt = 0; nt < 4; nt++)
                    acc[mt][nt] = __builtin_amdgcn_mfma_f32_16x16x32_bf16(
                        av[mt], bv[nt], acc[mt][nt], 0, 0, 0);
        }
        __syncthreads();
    }
#pragma unroll
    for (int nt = 0; nt < 4; nt++) {
        int dcol = d0 + wn*64 + nt*16 + m16;
        float bval = bias[dcol];
#pragma unroll
        for (int mt = 0; mt < 4; mt++) {
#pragma unroll
            for (int r = 0; r < 4; r++) {
                int n = n0 + wm*64 + mt*16 + quad*4 + r;
                if (n < N_)
                    out0[((size_t)b*N_ + n)*DIM_ + dcol] = acc[mt][nt][r] + bval;
            }
        }
    }
}

// ---------------------------------------------------------------------------
// k6 fallback (fp32 A staging, used only if ws too small for swb)
__global__ __launch_bounds__(256) void k6_fp(
        const float* __restrict__ sw,
        const unsigned short* __restrict__ Pbf,
        const float* __restrict__ bias,
        float* __restrict__ out0) {
    __shared__ unsigned short As[128*64];
    __shared__ unsigned short Bs[128*64];
    int d0 = blockIdx.x * 128;
    int n0 = blockIdx.y * 128;
    int b  = blockIdx.z;
    int tid = threadIdx.x;
    int lane = tid & 63, wid = tid >> 6;
    int wm = wid & 1, wn = wid >> 1;
    int quad = lane >> 4, m16 = lane & 15;

    f32x4 acc[4][4] = {};

    for (int kt = 0; kt < 8; kt++) {
        const float* Ab = sw + ((size_t)(b*8 + kt) * N_ + n0) * 64;
#pragma unroll
        for (int r = 0; r < 8; r++) {
            int f = r*256 + tid;
            int nl = f >> 4;
            float4 v = make_float4(0.f,0.f,0.f,0.f);
            if (n0 + nl < N_) v = ((const float4*)Ab)[f];
            ushort4 o;
            o.x = f2bf(v.x); o.y = f2bf(v.y); o.z = f2bf(v.z); o.w = f2bf(v.w);
            *(ushort4*)&As[f*4] = o;
        }
        const unsigned short* Bb = Pbf + ((size_t)(b*512) + d0)*512 + kt*64;
#pragma unroll
        for (int c = wid; c < 16; c += 4) {
            const unsigned short* gp = Bb + (size_t)(c*8 + (lane >> 3))*512 + (lane & 7)*8;
            __builtin_amdgcn_global_load_lds(
                (const __attribute__((address_space(1))) unsigned int*)gp,
                (__attribute__((address_space(3))) unsigned int*)&Bs[c*512],
                16, 0, 0);
        }
        __syncthreads();
#pragma unroll
        for (int ks = 0; ks < 2; ks++) {
            short8 av[4], bv[4];
#pragma unroll
            for (int mt = 0; mt < 4; mt++)
                av[mt] = *(short8*)&As[(wm*64 + mt*16 + m16)*64 + ks*32 + quad*8];
#pragma unroll
            for (int nt = 0; nt < 4; nt++)
                bv[nt] = *(short8*)&Bs[(wn*64 + nt*16 + m16)*64 + ks*32 + quad*8];
#pragma unroll
            for (int mt = 0; mt < 4; mt++)
#pragma unroll
                for (int nt = 0; nt < 4; nt++)
                    acc[mt][nt] = __builtin_amdgcn_mfma_f32_16x16x32_bf16(
                        av[mt], bv[nt], acc[mt][nt], 0, 0, 0);
        }
        __syncthreads();
    }
#pragma unroll
    for (int nt = 0; nt < 4; nt++) {
        int dcol = d0 + wn*64 + nt*16 + m16;
        float bval = bias[dcol];
#pragma unroll
        for (int mt = 0; mt < 4; mt++) {
#pragma unroll
            for (int r = 0; r < 4; r++) {
                int n = n0 + wm*64 + mt*16 + quad*4 + r;
                if (n < N_)
                    out0[((size_t)b*N_ + n)*DIM_ + dcol] = acc[mt][nt][r] + bval;
            }
        }
    }
}

// ---------------------------------------------------------------------------
extern "C" void kernel_launch(void* const* d_in, const int* in_sizes, int n_in,
                              void* d_out, int out_size, void* d_ws, size_t ws_size,
                              hipStream_t stream) {
    const float* st      = (const float*)d_in[0];
    const float* sw      = (const float*)d_in[1];
    const float* w_in    = (const float*)d_in[2];
    const float* conv_w  = (const float*)d_in[3];
    const float* conv_b  = (const float*)d_in[4];
    const float* dt_bias = (const float*)d_in[5];
    const float* A_log   = (const float*)d_in[6];
    const float* Dvec    = (const float*)d_in[7];
    const float* fc_D_w  = (const float*)d_in[8];
    const float* norm_w  = (const float*)d_in[9];
    const float* w_out   = (const float*)d_in[10];
    const float* to_out_w= (const float*)d_in[11];
    const float* to_out_b= (const float*)d_in[12];
    float* out = (float*)d_out;
    float* ws  = (float*)d_ws;

    // layout (floats): [Pbf][temporaries | swb (aliases temporaries, used after k5)]
    unsigned short* Pbf = (unsigned short*)ws;                 // 4,194,304 us = 2,097,152 fl
    float* base = ws + 2097152;
    float* zx   = base;                                        // 1,067,008
    float* xb   = zx  + (size_t)B_*G_*DINPROJ_;                // 524,288
    float* zs   = xb  + (size_t)B_*G_*DM_;                     // 524,288
    float* tblf = zs  + (size_t)B_*G_*DM_;                     // 32,768
    float* Cv   = tblf+ (size_t)B_*G_*NH_*4;                   // 1,024
    float* dco  = Cv  + B_*G_;                                 // 8,192
    float* yfw  = dco + B_*G_*NH_;                             // 524,288
    float* ybw  = yfw + (size_t)B_*G_*DM_;                     // 524,288
    float* yn   = ybw + (size_t)B_*G_*DM_;                     // 524,288
    float* om   = yn  + (size_t)B_*G_*DM_;                     // 524,288
    // swb aliases [base ..): needs 12,824,576 us + pad; k0 runs after k5.
    unsigned short* swb = (unsigned short*)base;
    size_t need_async = (2097152 + 6416384) * sizeof(float);   // ~34.1 MB
    bool async_ok = ws_size >= need_async;

    dim3 g1(17, 16);
    k1_inproj<<<g1, 256, 0, stream>>>(st, w_in, zx);
    k2_conv  <<<B_*G_, 256, 0, stream>>>(zx, conv_w, conv_b, dt_bias, A_log,
                                         fc_D_w, Dvec, xb, zs, Cv, tblf, dco);
    dim3 g3(B_*HEADS_, 2);
    k3_scan  <<<g3, 64, 0, stream>>>(xb, Cv, tblf, dco, yfw, ybw);
    k4a_rms  <<<B_*G_, 256, 0, stream>>>(yfw, ybw, zs, norm_w, yn);
    dim3 g4(8, 16);
    k4b_wout <<<g4, 256, 0, stream>>>(yn, w_out, om, out + OUT2_OFS);
    k5_P     <<<B_*HEADS_, 256, 0, stream>>>(om, to_out_w, Pbf);
    dim3 g6(4, 25, 16);
    if (async_ok) {
        k0_cvt<<<SW_ELEMS/8/256, 256, 0, stream>>>(sw, swb);
        k6_bf <<<g6, 256, 0, stream>>>(swb, Pbf, to_out_b, out + OUT0_OFS);
    } else {
        k6_fp <<<g6, 256, 0, stream>>>(sw, Pbf, to_out_b, out + OUT0_OFS);
    }
    hipMemcpyAsync(out + OUT1_OFS, st, (size_t)B_*HEADS_*G_*DH_*sizeof(float),
                   hipMemcpyDeviceToDevice, stream);
}